// Round 3
// baseline (275.432 us; speedup 1.0000x reference)
//
#include <hip/hip_runtime.h>
#include <hip/hip_bf16.h>
#include <stdint.h>

#define N1 8192
#define N2 8192
#define DK 128
#define BM 128
#define BN 128
#define BK 32
#define LDA (BM + 4)
#define LDB (BN + 4)

// Module-scope device scratch (graph-capture safe, no d_ws dependence).
__device__ unsigned long long g_rowmax[N1];
__device__ unsigned long long g_colmax[N2];
__device__ int g_nn12[N1];
__device__ int g_nn21[N2];

// Monotone pack: larger sim value wins; on exact tie, smaller index wins
// (numpy argmax first-occurrence semantics) because we store ~idx.
__device__ __forceinline__ unsigned long long packmax(float v, unsigned idx) {
    unsigned u = __float_as_uint(v);
    u ^= (u & 0x80000000u) ? 0xFFFFFFFFu : 0x80000000u;
    return ((unsigned long long)u << 32) | (unsigned)(~idx);
}

__global__ void init_max_kernel() {
    int i = blockIdx.x * blockDim.x + threadIdx.x;
    if (i < N1) g_rowmax[i] = 0ULL;               // 0 is below any real key
    else if (i < N1 + N2) g_colmax[i - N1] = 0ULL;
}

__global__ __launch_bounds__(256) void sim_kernel(
    const float* __restrict__ A, const float* __restrict__ B)
{
    __shared__ __align__(16) float lds[BK * LDA + BK * LDB];  // 33792 B
    float* as = lds;             // [BK][LDA]  as[k][m]
    float* bs = lds + BK * LDA;  // [BK][LDB]  bs[k][n]

    const int tid = threadIdx.x;
    const int tm = tid >> 4;   // 0..15 -> rows tm*8..tm*8+7
    const int tn = tid & 15;   // 0..15 -> cols tn*8..tn*8+7
    const int row0 = blockIdx.y * BM;
    const int col0 = blockIdx.x * BN;

    float acc[8][8];
#pragma unroll
    for (int r = 0; r < 8; ++r)
#pragma unroll
        for (int c = 0; c < 8; ++c) acc[r][c] = 0.f;

    for (int k0 = 0; k0 < DK; k0 += BK) {
        // stage A[128x32], B[128x32] -> LDS transposed (k-major)
#pragma unroll
        for (int q = 0; q < 4; ++q) {
            int f = q * 256 + tid;       // 0..1023
            int r = f >> 3;              // 0..127
            int c4 = f & 7;              // 0..7
            const float4 av = *reinterpret_cast<const float4*>(A + (size_t)(row0 + r) * DK + k0 + c4 * 4);
            const float4 bv = *reinterpret_cast<const float4*>(B + (size_t)(col0 + r) * DK + k0 + c4 * 4);
            int kb = c4 * 4;
            as[(kb + 0) * LDA + r] = av.x;
            as[(kb + 1) * LDA + r] = av.y;
            as[(kb + 2) * LDA + r] = av.z;
            as[(kb + 3) * LDA + r] = av.w;
            bs[(kb + 0) * LDB + r] = bv.x;
            bs[(kb + 1) * LDB + r] = bv.y;
            bs[(kb + 2) * LDB + r] = bv.z;
            bs[(kb + 3) * LDB + r] = bv.w;
        }
        __syncthreads();

        for (int kk = 0; kk < BK; ++kk) {
            float a[8], b[8];
            float4 a0 = *reinterpret_cast<float4*>(&as[kk * LDA + tm * 8]);
            float4 a1 = *reinterpret_cast<float4*>(&as[kk * LDA + tm * 8 + 4]);
            float4 b0 = *reinterpret_cast<float4*>(&bs[kk * LDB + tn * 8]);
            float4 b1 = *reinterpret_cast<float4*>(&bs[kk * LDB + tn * 8 + 4]);
            a[0] = a0.x; a[1] = a0.y; a[2] = a0.z; a[3] = a0.w;
            a[4] = a1.x; a[5] = a1.y; a[6] = a1.z; a[7] = a1.w;
            b[0] = b0.x; b[1] = b0.y; b[2] = b0.z; b[3] = b0.w;
            b[4] = b1.x; b[5] = b1.y; b[6] = b1.z; b[7] = b1.w;
#pragma unroll
            for (int r = 0; r < 8; ++r)
#pragma unroll
                for (int c = 0; c < 8; ++c)
                    acc[r][c] = fmaf(a[r], b[c], acc[r][c]);
        }
        __syncthreads();
    }

    // ---- fused argmax epilogue (reuse LDS as uint64[128][16]) ----
    unsigned long long* red = reinterpret_cast<unsigned long long*>(lds);

    // row phase: per-row max over this tile's 128 columns
#pragma unroll
    for (int r = 0; r < 8; ++r) {
        unsigned long long best = 0ULL;
#pragma unroll
        for (int c = 0; c < 8; ++c) {
            unsigned long long pk = packmax(acc[r][c], (unsigned)(col0 + tn * 8 + c));
            best = best > pk ? best : pk;
        }
        red[(tm * 8 + r) * 16 + tn] = best;
    }
    __syncthreads();
    if (tid < 128) {
        unsigned long long best = 0ULL;
#pragma unroll
        for (int t = 0; t < 16; ++t) {
            unsigned long long pk = red[tid * 16 + t];
            best = best > pk ? best : pk;
        }
        atomicMax(&g_rowmax[row0 + tid], best);
    }
    __syncthreads();

    // col phase: per-col max over this tile's 128 rows
#pragma unroll
    for (int c = 0; c < 8; ++c) {
        unsigned long long best = 0ULL;
#pragma unroll
        for (int r = 0; r < 8; ++r) {
            unsigned long long pk = packmax(acc[r][c], (unsigned)(row0 + tm * 8 + r));
            best = best > pk ? best : pk;
        }
        red[(tn * 8 + c) * 16 + tm] = best;
    }
    __syncthreads();
    if (tid < 128) {
        unsigned long long best = 0ULL;
#pragma unroll
        for (int t = 0; t < 16; ++t) {
            unsigned long long pk = red[tid * 16 + t];
            best = best > pk ? best : pk;
        }
        atomicMax(&g_colmax[col0 + tid], best);
    }
}

__global__ void extract_kernel(float* __restrict__ out)
{
    int i = blockIdx.x * blockDim.x + threadIdx.x;
    if (i < N1) {
        unsigned long long p = g_rowmax[i];
        unsigned key = (unsigned)(p >> 32);
        unsigned vb = key ^ ((key & 0x80000000u) ? 0x80000000u : 0xFFFFFFFFu);
        out[N1 + i] = __uint_as_float(vb);        // scores (float32)
        g_nn12[i] = (int)(~(unsigned)p);
    } else if (i < N1 + N2) {
        int j = i - N1;
        g_nn21[j] = (int)(~(unsigned)g_colmax[j]);
    }
}

__global__ void mutual_kernel(float* __restrict__ out)
{
    int i = blockIdx.x * blockDim.x + threadIdx.x;
    if (i < N1) {
        int m = g_nn12[i];
        int v = (g_nn21[m] == i) ? m : -1;
        out[i] = (float)v;                        // matches0 (float32)
    }
}

extern "C" void kernel_launch(void* const* d_in, const int* in_sizes, int n_in,
                              void* d_out, int out_size, void* d_ws, size_t ws_size,
                              hipStream_t stream) {
    const float* A = (const float*)d_in[0];   // desc1 [8192,128] f32
    const float* B = (const float*)d_in[1];   // desc2 [8192,128] f32
    float* out = (float*)d_out;               // [0:8192]=matches, [8192:16384]=scores

    init_max_kernel<<<(N1 + N2 + 255) / 256, 256, 0, stream>>>();
    dim3 grid(N2 / BN, N1 / BM);
    sim_kernel<<<grid, 256, 0, stream>>>(A, B);
    extract_kernel<<<(N1 + N2 + 255) / 256, 256, 0, stream>>>(out);
    mutual_kernel<<<(N1 + 255) / 256, 256, 0, stream>>>(out);
}